// Round 24
// baseline (225.413 us; speedup 1.0000x reference)
//
#include <hip/hip_runtime.h>
#include <hip/hip_fp16.h>
#include <hip/hip_cooperative_groups.h>
#include <math.h>

namespace cg = cooperative_groups;

#define B_ 2
#define C_ 256
#define H_ 64
#define W_ 64
#define L_ 4096
#define HEADS_ 8
#define K_ 7
#define PAD_ 3
#define K2_ 49
#define PW_ 70
#define PPIX_ 4900
#define NPP_ 4                                  // pair-planes (8ch) per (b,h)
#define PADT4_ ((size_t)B_*HEADS_*NPP_*PPIX_)   // 313600 uint4 per padded tensor
#define WS_STR 72                               // LDS row stride in f16 elems (144B)
#define KVW_ (NPP_*K_*PW_)                      // 1960 uint4 staged window

typedef _Float16 f16x8 __attribute__((ext_vector_type(8)));
typedef _Float16 h2    __attribute__((ext_vector_type(2)));
typedef float    f32x4 __attribute__((ext_vector_type(4)));

__device__ inline h2 u2h(unsigned u) { union { unsigned u; h2 h; } c; c.u = u; return c.h; }
__device__ inline h2 cvt2h(float a, float b) {
    auto r = __builtin_amdgcn_cvt_pkrtz(a, b);      // __fp16 ext_vector(2)
    union { decltype(r) s; h2 d; } c; c.s = r; return c.d;
}
__device__ inline unsigned pkh(float a, float b) {
    union { h2 h; unsigned u; } c; c.h = cvt2h(a, b); return c.u;
}

// One cooperative kernel, 4 phases separated by grid.sync().
// Phase 0: weight pack (f16) + K/V halo zero.
// Phase 1: QKV projection via f16 MFMA (768 logical blocks, grid-stride).
// Phase 2: 7x7 local attention, LDS-staged K/V window (1024 logical blocks).
// Phase 3: output projection via f16 MFMA (512 logical blocks).
__global__ __launch_bounds__(256, 2) void fused(
    const float* __restrict__ q_in, const float* __restrict__ k_in, const float* __restrict__ v_in,
    const float* __restrict__ wq, const float* __restrict__ bq,
    const float* __restrict__ wk, const float* __restrict__ bk,
    const float* __restrict__ wv, const float* __restrict__ bv,
    const float* __restrict__ wo, const float* __restrict__ bo,
    float* __restrict__ out,
    uint4* __restrict__ qt, uint4* __restrict__ kt, uint4* __restrict__ vt,
    unsigned* __restrict__ wb)
{
    cg::grid_group grid = cg::this_grid();
    const int tid = threadIdx.x;
    const int pbid = blockIdx.x;
    const int gstep = gridDim.x * 256;

    __shared__ __align__(16) char smem[43904];   // max(qkv 27.6KB, attn 43.9KB, out 18.4KB)

    // ================= Phase 0: weight pack + halo zero =================
    for (int idx = pbid*256 + tid; idx < 131072; idx += gstep) {
        const float* src = (idx < 32768) ? wq : (idx < 65536) ? wk : (idx < 98304) ? wv : wo;
        int off = (idx & 32767) * 2;
        wb[idx] = pkh(src[off], src[off+1]);
    }
    {
        const uint4 zz = make_uint4(0u,0u,0u,0u);
        for (int e = pbid*256 + tid; e < 64*804; e += gstep) {
            int pl = e / 804;
            int c  = e - pl*804;
            int py, px;
            if (c < 210)      { py = c/70;            px = c%70; }
            else if (c < 420) { int c2 = c-210; py = 67 + c2/70; px = c2%70; }
            else              { int c2 = c-420; py = 3 + c2/6; int j = c2%6; px = (j<3) ? j : 64+j; }
            size_t idx = (size_t)pl*PPIX_ + (size_t)py*PW_ + px;
            kt[idx] = zz;
            vt[idx] = zz;
        }
    }
    __threadfence();
    grid.sync();

    // ================= Phase 1: QKV projection (768 logical) =================
    const int lane = tid & 63, wave = tid >> 6;
    const int orow = lane & 15, kgrp = lane >> 4;
    uint2* qt_u2 = (uint2*)qt;
    uint2* kt_u2 = (uint2*)kt;
    uint2* vt_u2 = (uint2*)vt;

    for (int lb = pbid; lb < 768; lb += gridDim.x) {
        __syncthreads();
        const int y     = lb & 63;
        const int l0    = y * 64;
        const int o_t0  = ((lb >> 6) & 1) * 128;
        const int z     = lb >> 7;           // 0..5
        const int which = z >> 1;            // 0=q,1=k,2=v
        const int b     = z & 1;
        const float* X = (which==0) ? q_in : (which==1 ? k_in : v_in);
        const unsigned* wbp = wb + which*32768;
        const float* bias = (which==0) ? bq : (which==1 ? bk : bv);

        _Float16* Ws = (_Float16*)smem;               // 128*72 f16 = 18432B
        _Float16* Xs = (_Float16*)(smem + 18432);     // 64*72 f16  = 9216B

        f32x4 acc[2][4] = {};

        for (int ch = 0; ch < 4; ++ch) {
            const int c0 = ch*64;
            #pragma unroll
            for (int i = 0; i < 4; ++i) {
                int flat = i*256 + tid;
                int o    = flat >> 3;
                int c16  = flat & 7;
                uint4 v = *reinterpret_cast<const uint4*>(wbp + (size_t)(o_t0 + o)*128 + ch*32 + c16*4);
                *reinterpret_cast<uint4*>(&Ws[o*WS_STR + c16*8]) = v;
            }
            #pragma unroll
            for (int i = 0; i < 2; ++i) {
                int c_loc = (tid>>4)*2 + i*32;
                int l4    = (tid&15)*4;
                float4 x0 = *reinterpret_cast<const float4*>(&X[(size_t)(b*C_ + c0 + c_loc    )*L_ + l0 + l4]);
                float4 x1 = *reinterpret_cast<const float4*>(&X[(size_t)(b*C_ + c0 + c_loc + 1)*L_ + l0 + l4]);
                *reinterpret_cast<unsigned*>(&Xs[(l4+0)*WS_STR + c_loc]) = pkh(x0.x, x1.x);
                *reinterpret_cast<unsigned*>(&Xs[(l4+1)*WS_STR + c_loc]) = pkh(x0.y, x1.y);
                *reinterpret_cast<unsigned*>(&Xs[(l4+2)*WS_STR + c_loc]) = pkh(x0.z, x1.z);
                *reinterpret_cast<unsigned*>(&Xs[(l4+3)*WS_STR + c_loc]) = pkh(x0.w, x1.w);
            }
            __syncthreads();
            #pragma unroll
            for (int kk = 0; kk < 2; ++kk) {
                f16x8 af[2], bfr[4];
                #pragma unroll
                for (int fo = 0; fo < 2; ++fo)
                    af[fo] = *reinterpret_cast<const f16x8*>(&Ws[(wave*32 + fo*16 + orow)*WS_STR + kk*32 + kgrp*8]);
                #pragma unroll
                for (int fn = 0; fn < 4; ++fn)
                    bfr[fn] = *reinterpret_cast<const f16x8*>(&Xs[(fn*16 + orow)*WS_STR + kk*32 + kgrp*8]);
                #pragma unroll
                for (int fo = 0; fo < 2; ++fo)
                    #pragma unroll
                    for (int fn = 0; fn < 4; ++fn)
                        acc[fo][fn] = __builtin_amdgcn_mfma_f32_16x16x32_f16(af[fo], bfr[fn], acc[fo][fn], 0, 0, 0);
            }
            __syncthreads();
        }

        #pragma unroll
        for (int fo = 0; fo < 2; ++fo) {
            const int og = o_t0 + wave*32 + fo*16 + kgrp*4;
            const float4 b4 = *reinterpret_cast<const float4*>(&bias[og]);
            const size_t pp = (size_t)(b*32 + (og >> 3));
            const int half = (og >> 2) & 1;
            #pragma unroll
            for (int fn = 0; fn < 4; ++fn) {
                const int xl = fn*16 + orow;
                uint2 r = make_uint2(pkh(acc[fo][fn][0] + b4.x, acc[fo][fn][1] + b4.y),
                                     pkh(acc[fo][fn][2] + b4.z, acc[fo][fn][3] + b4.w));
                if (which == 0) {
                    qt_u2[(pp*L_ + l0 + xl)*2 + half] = r;
                } else {
                    uint2* dst = (which==1) ? kt_u2 : vt_u2;
                    dst[(pp*PPIX_ + (size_t)(y+PAD_)*PW_ + (xl+PAD_))*2 + half] = r;
                }
            }
        }
    }
    __threadfence();
    grid.sync();

    // ================= Phase 2: local attention (1024 logical) =================
    {
        const int w = tid >> 6, x = tid & 63;
        const float scale = 0.0625f; // 1/sqrt(256)
        uint4* KV = (uint4*)smem;                    // 1960 uint4 = 31360B
        float* S  = (float*)(smem + 31360);          // 49*64 f32 = 12544B

        for (int lb = pbid; lb < 1024; lb += gridDim.x) {
            __syncthreads();
            const int plane = lb & 15;
            const int y = lb >> 4;

            const uint4* kb = kt + (size_t)plane*NPP_*PPIX_;
            const uint4* vb = vt + (size_t)plane*NPP_*PPIX_;
            uint4* qpl = qt + (size_t)plane*NPP_*L_;

            uint4 qu[NPP_];
            #pragma unroll
            for (int pp=0; pp<NPP_; ++pp) qu[pp] = qpl[(size_t)pp*L_ + y*W_ + x];

            #pragma unroll
            for (int i = 0; i < 8; ++i) {
                int e = tid + i*256;
                if (e < KVW_) {
                    int pp = e / (K_*PW_);
                    int rem = e - pp*(K_*PW_);
                    int r = rem / PW_, xp = rem - r*PW_;
                    KV[e] = kb[(size_t)pp*PPIX_ + (size_t)(y + r)*PW_ + xp];
                }
            }
            __syncthreads();

            float lg[2][K_] = {};
            #pragma unroll
            for (int pp=0; pp<NPP_; ++pp) {
                const h2 q0 = u2h(qu[pp].x), q1 = u2h(qu[pp].y), q2 = u2h(qu[pp].z), q3 = u2h(qu[pp].w);
                #pragma unroll
                for (int rr=0; rr<2; ++rr) {
                    const int r = w + rr*4;
                    if (r > 6) continue;
                    const uint4* row = &KV[(pp*K_ + r)*PW_ + x];
                    #pragma unroll
                    for (int kx=0; kx<K_; ++kx) {
                        uint4 kk = row[kx];
                        float d = lg[rr][kx];
                        d = __builtin_amdgcn_fdot2(q0, u2h(kk.x), d, false);
                        d = __builtin_amdgcn_fdot2(q1, u2h(kk.y), d, false);
                        d = __builtin_amdgcn_fdot2(q2, u2h(kk.z), d, false);
                        d = __builtin_amdgcn_fdot2(q3, u2h(kk.w), d, false);
                        lg[rr][kx] = d;
                    }
                }
            }
            #pragma unroll
            for (int rr=0; rr<2; ++rr) {
                const int r = w + rr*4;
                if (r <= 6) {
                    #pragma unroll
                    for (int kx=0; kx<K_; ++kx) S[(r*K_+kx)*64 + x] = __expf(lg[rr][kx]*scale);
                }
            }
            __syncthreads();   // S complete AND all K reads of KV done

            #pragma unroll
            for (int i = 0; i < 8; ++i) {
                int e = tid + i*256;
                if (e < KVW_) {
                    int pp = e / (K_*PW_);
                    int rem = e - pp*(K_*PW_);
                    int r = rem / PW_, xp = rem - r*PW_;
                    KV[e] = vb[(size_t)pp*PPIX_ + (size_t)(y + r)*PW_ + xp];
                }
            }

            float sum = 0.f;
            #pragma unroll
            for (int i=0;i<K2_;++i) sum += S[i*64 + x];
            const float inv = 1.0f/sum;
            __syncthreads();   // V staged

            float4 a0 = make_float4(0.f,0.f,0.f,0.f);
            float4 a1 = make_float4(0.f,0.f,0.f,0.f);
            #pragma unroll
            for (int r=0; r<K_; ++r) {
                const uint4* row = &KV[(w*K_ + r)*PW_ + x];
                h2 ra0 = (h2)0, ra1 = (h2)0, rb0 = (h2)0, rb1 = (h2)0;
                #pragma unroll
                for (int kx=0; kx<K_; ++kx) {
                    const float p = S[(r*K_+kx)*64 + x];
                    const h2 p2 = cvt2h(p, p);
                    uint4 u = row[kx];
                    ra0 += p2 * u2h(u.x);
                    ra1 += p2 * u2h(u.y);
                    rb0 += p2 * u2h(u.z);
                    rb1 += p2 * u2h(u.w);
                }
                a0.x += (float)ra0[0]; a0.y += (float)ra0[1];
                a0.z += (float)ra1[0]; a0.w += (float)ra1[1];
                a1.x += (float)rb0[0]; a1.y += (float)rb0[1];
                a1.z += (float)rb1[0]; a1.w += (float)rb1[1];
            }
            qpl[(size_t)w*L_ + y*W_ + x] = make_uint4(pkh(a0.x*inv, a0.y*inv), pkh(a0.z*inv, a0.w*inv),
                                                      pkh(a1.x*inv, a1.y*inv), pkh(a1.z*inv, a1.w*inv));
        }
    }
    __threadfence();
    grid.sync();

    // ================= Phase 3: output projection (512 logical) =================
    {
        const unsigned* wbp = wb + 3*32768;
        const int cq  = tid >> 6;
        const int lst = tid & 63;
        _Float16* Ws = (_Float16*)smem;              // 64*72 = 9216B
        _Float16* Xs = (_Float16*)(smem + 9216);     // 64*72 = 9216B

        for (int lb = pbid; lb < 512; lb += gridDim.x) {
            __syncthreads();
            const int l0   = (lb & 63) * 64;
            const int o_t0 = ((lb >> 6) & 3) * 64;
            const int b    = lb >> 8;

            f32x4 acc[4] = {};

            for (int ch = 0; ch < 4; ++ch) {
                const int c0 = ch*64;
                #pragma unroll
                for (int i = 0; i < 2; ++i) {
                    int flat = i*256 + tid;
                    int o    = flat >> 3;
                    int c16  = flat & 7;
                    uint4 v = *reinterpret_cast<const uint4*>(wbp + (size_t)(o_t0 + o)*128 + ch*32 + c16*4);
                    *reinterpret_cast<uint4*>(&Ws[o*WS_STR + c16*8]) = v;
                }
                #pragma unroll
                for (int i = 0; i < 2; ++i) {
                    int c8 = i*4 + cq;
                    uint4 v = qt[((size_t)b*32 + (c0>>3) + c8)*L_ + l0 + lst];
                    *reinterpret_cast<uint4*>(&Xs[lst*WS_STR + c8*8]) = v;
                }
                __syncthreads();
                #pragma unroll
                for (int kk = 0; kk < 2; ++kk) {
                    f16x8 af, bfr[4];
                    af = *reinterpret_cast<const f16x8*>(&Ws[(wave*16 + orow)*WS_STR + kk*32 + kgrp*8]);
                    #pragma unroll
                    for (int fn = 0; fn < 4; ++fn)
                        bfr[fn] = *reinterpret_cast<const f16x8*>(&Xs[(fn*16 + orow)*WS_STR + kk*32 + kgrp*8]);
                    #pragma unroll
                    for (int fn = 0; fn < 4; ++fn)
                        acc[fn] = __builtin_amdgcn_mfma_f32_16x16x32_f16(af, bfr[fn], acc[fn], 0, 0, 0);
                }
                __syncthreads();
            }

            const int o_base = o_t0 + wave*16 + kgrp*4;
            #pragma unroll
            for (int fn = 0; fn < 4; ++fn) {
                const int xl = fn*16 + orow;
                #pragma unroll
                for (int r = 0; r < 4; ++r)
                    out[(size_t)(b*C_ + o_base + r)*L_ + l0 + xl] = acc[fn][r] + bo[o_base + r];
            }
        }
    }
}

extern "C" void kernel_launch(void* const* d_in, const int* in_sizes, int n_in,
                              void* d_out, int out_size, void* d_ws, size_t ws_size,
                              hipStream_t stream) {
    const float* queries = (const float*)d_in[0];
    const float* keys    = (const float*)d_in[1];
    const float* values  = (const float*)d_in[2];
    const float* wq = (const float*)d_in[3];
    const float* bq = (const float*)d_in[4];
    const float* wk = (const float*)d_in[5];
    const float* bk = (const float*)d_in[6];
    const float* wv = (const float*)d_in[7];
    const float* bv = (const float*)d_in[8];
    const float* wo = (const float*)d_in[9];
    const float* bo = (const float*)d_in[10];
    float* out = (float*)d_out;

    uint4* qt = (uint4*)d_ws;                              // Q f16 pair-plane, attn out in-place
    uint4* kt = qt + (size_t)B_*HEADS_*NPP_*L_;            // padded pair-plane K
    uint4* vt = kt + PADT4_;                               // padded pair-plane V
    unsigned* wb = (unsigned*)(vt + PADT4_);               // f16 packed weights

    // Size the cooperative grid from the occupancy API (deterministic),
    // capped at 2 blocks/CU so co-residency is guaranteed.
    int maxB = 0;
    hipOccupancyMaxActiveBlocksPerMultiprocessor(&maxB, (const void*)fused, 256, 0);
    if (maxB < 1) maxB = 1;
    if (maxB > 2) maxB = 2;
    int grid = maxB * 256;

    void* args[] = { (void*)&queries, (void*)&keys, (void*)&values,
                     (void*)&wq, (void*)&bq, (void*)&wk, (void*)&bk,
                     (void*)&wv, (void*)&bv, (void*)&wo, (void*)&bo,
                     (void*)&out, (void*)&qt, (void*)&kt, (void*)&vt, (void*)&wb };
    hipLaunchCooperativeKernel((const void*)fused, dim3(grid), dim3(256), args, 0, stream);
}

// Round 25
// 46.373 us; speedup vs baseline: 4.8609x; 4.8609x over previous
//
#include <hip/hip_runtime.h>
#include <hip/hip_fp16.h>
#include <math.h>

#define B_ 2
#define C_ 256
#define H_ 64
#define W_ 64
#define L_ 4096
#define HEADS_ 8
#define DH_ 32
#define K_ 7
#define PAD_ 3
#define K2_ 49
#define PW_ 70
#define PPIX_ 4900
#define NPP_ 4                                  // pair-planes (8ch) per (b,h)
#define PADT4_ ((size_t)B_*HEADS_*NPP_*PPIX_)   // 313600 uint4 per padded tensor
#define WS_STR 72                               // LDS row stride in f16 elems (144B = 9x16B)
#define KVW_ (NPP_*K_*PW_)                      // 1960 uint4 staged window

typedef _Float16 f16x8 __attribute__((ext_vector_type(8)));
typedef _Float16 h2    __attribute__((ext_vector_type(2)));
typedef float    f32x4 __attribute__((ext_vector_type(4)));

__device__ inline h2 u2h(unsigned u) { union { unsigned u; h2 h; } c; c.u = u; return c.h; }
__device__ inline h2 cvt2h(float a, float b) {
    auto r = __builtin_amdgcn_cvt_pkrtz(a, b);      // __fp16 ext_vector(2)
    union { decltype(r) s; h2 d; } c; c.s = r; return c.d;
}
__device__ inline unsigned pkh(float a, float b) {
    union { h2 h; unsigned u; } c; c.h = cvt2h(a, b); return c.u;
}

// ---------------- Kernel A: weight pack (f16) ------------------------------
__global__ __launch_bounds__(256) void prep(
    const float* __restrict__ wq, const float* __restrict__ wk,
    const float* __restrict__ wv, const float* __restrict__ wo,
    unsigned* __restrict__ wb)
{
    int idx = blockIdx.x*256 + threadIdx.x;   // 0..131071
    const float* src = (idx < 32768) ? wq : (idx < 65536) ? wk : (idx < 98304) ? wv : wo;
    int off = (idx & 32767) * 2;
    wb[idx] = pkh(src[off], src[off+1]);
}

// ---------------- Kernel B: QKV projection via f16 MFMA + halo-zero slice ---
// z = 0..5: GEMM (which = z>>1, b = z&1), 128 o x 64 l per block.
// z = 6:    K/V halo zeroing (uint4 pair-plane layout, direct enumeration).
__global__ __launch_bounds__(256) void qkv_mfma(
    const float* __restrict__ q_in, const float* __restrict__ k_in, const float* __restrict__ v_in,
    const unsigned* __restrict__ wb,
    const float* __restrict__ bq, const float* __restrict__ bk, const float* __restrict__ bv,
    uint2* __restrict__ qt_u2, uint2* __restrict__ kt_u2, uint2* __restrict__ vt_u2,
    uint4* __restrict__ kt_u4, uint4* __restrict__ vt_u4)
{
    const int z = blockIdx.z;
    const int tid = threadIdx.x;

    if (z == 6) {
        // zero halo cells of 64 pair-planes: top3/bottom3 rows (420) + 64x6 (384)
        const int flat = blockIdx.x + 64*blockIdx.y;   // 0..127
        const uint4 zz = make_uint4(0u,0u,0u,0u);
        for (int e = flat*256 + tid; e < 64*804; e += 128*256) {
            int pl = e / 804;
            int c  = e - pl*804;
            int py, px;
            if (c < 210)      { py = c/70;            px = c%70; }
            else if (c < 420) { int c2 = c-210; py = 67 + c2/70; px = c2%70; }
            else              { int c2 = c-420; py = 3 + c2/6; int j = c2%6; px = (j<3) ? j : 64+j; }
            size_t idx = (size_t)pl*PPIX_ + (size_t)py*PW_ + px;
            kt_u4[idx] = zz;
            vt_u4[idx] = zz;
        }
        return;
    }

    const int which = z >> 1;      // 0=q,1=k,2=v
    const int b = z & 1;
    const float* X = (which==0) ? q_in : (which==1 ? k_in : v_in);
    const unsigned* wbp = wb + which*32768;
    const float* bias = (which==0) ? bq : (which==1 ? bk : bv);

    const int y    = blockIdx.x;
    const int l0   = y * 64;
    const int o_t0 = blockIdx.y * 128;
    const int lane = tid & 63, wave = tid >> 6;
    const int orow = lane & 15, kgrp = lane >> 4;

    __shared__ _Float16 Ws[128*WS_STR];   // weights [o][c-chunk]  (18.4 KB)
    __shared__ _Float16 Xs[64*WS_STR];    // input^T [l][c-chunk]  (9.2 KB)

    f32x4 acc[2][4] = {};

    for (int ch = 0; ch < 4; ++ch) {
        const int c0 = ch*64;
        // Ws staging: uint4 (4 loads + 4 16B ds-writes per thread per chunk)
        #pragma unroll
        for (int i = 0; i < 4; ++i) {
            int flat = i*256 + tid;             // 0..1023
            int o    = flat >> 3;               // 0..127
            int c16  = flat & 7;                // uint4 index within 64-c chunk
            uint4 v = *reinterpret_cast<const uint4*>(wbp + (size_t)(o_t0 + o)*128 + ch*32 + c16*4);
            *reinterpret_cast<uint4*>(&Ws[o*WS_STR + c16*8]) = v;
        }
        // Xs staging: paired-c float4 loads, packed u32 transpose writes
        #pragma unroll
        for (int i = 0; i < 2; ++i) {
            int c_loc = (tid>>4)*2 + i*32;      // even c: 0,2,..,62
            int l4    = (tid&15)*4;             // 0,4,...,60
            float4 x0 = *reinterpret_cast<const float4*>(&X[(size_t)(b*C_ + c0 + c_loc    )*L_ + l0 + l4]);
            float4 x1 = *reinterpret_cast<const float4*>(&X[(size_t)(b*C_ + c0 + c_loc + 1)*L_ + l0 + l4]);
            *reinterpret_cast<unsigned*>(&Xs[(l4+0)*WS_STR + c_loc]) = pkh(x0.x, x1.x);
            *reinterpret_cast<unsigned*>(&Xs[(l4+1)*WS_STR + c_loc]) = pkh(x0.y, x1.y);
            *reinterpret_cast<unsigned*>(&Xs[(l4+2)*WS_STR + c_loc]) = pkh(x0.z, x1.z);
            *reinterpret_cast<unsigned*>(&Xs[(l4+3)*WS_STR + c_loc]) = pkh(x0.w, x1.w);
        }
        __syncthreads();
        #pragma unroll
        for (int kk = 0; kk < 2; ++kk) {
            f16x8 af[2], bfr[4];
            #pragma unroll
            for (int fo = 0; fo < 2; ++fo)
                af[fo] = *reinterpret_cast<const f16x8*>(&Ws[(wave*32 + fo*16 + orow)*WS_STR + kk*32 + kgrp*8]);
            #pragma unroll
            for (int fn = 0; fn < 4; ++fn)
                bfr[fn] = *reinterpret_cast<const f16x8*>(&Xs[(fn*16 + orow)*WS_STR + kk*32 + kgrp*8]);
            #pragma unroll
            for (int fo = 0; fo < 2; ++fo)
                #pragma unroll
                for (int fn = 0; fn < 4; ++fn)
                    acc[fo][fn] = __builtin_amdgcn_mfma_f32_16x16x32_f16(af[fo], bfr[fn], acc[fo][fn], 0, 0, 0);
        }
        __syncthreads();
    }

    #pragma unroll
    for (int fo = 0; fo < 2; ++fo) {
        const int og = o_t0 + wave*32 + fo*16 + kgrp*4;
        const float4 b4 = *reinterpret_cast<const float4*>(&bias[og]);
        const size_t pp = (size_t)(b*32 + (og >> 3));   // pair-plane index
        const int half = (og >> 2) & 1;
        #pragma unroll
        for (int fn = 0; fn < 4; ++fn) {
            const int xl = fn*16 + orow;
            uint2 r = make_uint2(pkh(acc[fo][fn][0] + b4.x, acc[fo][fn][1] + b4.y),
                                 pkh(acc[fo][fn][2] + b4.z, acc[fo][fn][3] + b4.w));
            if (which == 0) {
                qt_u2[(pp*L_ + l0 + xl)*2 + half] = r;
            } else {
                uint2* dst = (which==1) ? kt_u2 : vt_u2;
                dst[(pp*PPIX_ + (size_t)(y+PAD_)*PW_ + (xl+PAD_))*2 + half] = r;
            }
        }
    }
}

// ---------------- Kernel C: 7x7 local attention, LDS-staged K/V window ------
// Block = (plane=b*8+h, image row y), 256 threads (4 waves), grid 1024.
__global__ __launch_bounds__(256) void local_attn(
    uint4* __restrict__ qt, const uint4* __restrict__ kt, const uint4* __restrict__ vt)
{
    const int tid = threadIdx.x;
    const int w = tid >> 6, x = tid & 63;
    const int bid = blockIdx.x;
    const int plane = bid & 15;      // plane -> XCD plane%8: K/V L2-resident per XCD
    const int y = bid >> 4;          // 0..63

    const uint4* kb = kt + (size_t)plane*NPP_*PPIX_;
    const uint4* vb = vt + (size_t)plane*NPP_*PPIX_;
    uint4* qpl = qt + (size_t)plane*NPP_*L_;

    __shared__ uint4 KV[KVW_];       // [pp][r 0..6][xp 0..69]: 31.36 KB
    __shared__ float S[K2_][64];     // P = exp(logit*scale): 12.25 KB  (43.9 KB total)

    const float scale = 0.0625f; // 1/sqrt(256)

    // ---- Q loads first (latency overlaps K staging) ----
    uint4 qu[NPP_];
    #pragma unroll
    for (int pp=0; pp<NPP_; ++pp) qu[pp] = qpl[(size_t)pp*L_ + y*W_ + x];

    // ---- stage K window: pure uint4 copy, fully coalesced ----
    #pragma unroll
    for (int i = 0; i < 8; ++i) {
        int e = tid + i*256;
        if (e < KVW_) {
            int pp = e / (K_*PW_);
            int rem = e - pp*(K_*PW_);
            int r = rem / PW_, xp = rem - r*PW_;
            KV[e] = kb[(size_t)pp*PPIX_ + (size_t)(y + r)*PW_ + xp];
        }
    }
    __syncthreads();

    // ---- QK: my window rows r = w and w+4, from LDS ----
    float lg[2][K_] = {};
    #pragma unroll
    for (int pp=0; pp<NPP_; ++pp) {
        const h2 q0 = u2h(qu[pp].x), q1 = u2h(qu[pp].y), q2 = u2h(qu[pp].z), q3 = u2h(qu[pp].w);
        #pragma unroll
        for (int rr=0; rr<2; ++rr) {
            const int r = w + rr*4;
            if (r > 6) continue;                  // only w=3,rr=1 skips (uniform)
            const uint4* row = &KV[(pp*K_ + r)*PW_ + x];
            #pragma unroll
            for (int kx=0; kx<K_; ++kx) {
                uint4 kk = row[kx];
                float d = lg[rr][kx];
                d = __builtin_amdgcn_fdot2(q0, u2h(kk.x), d, false);
                d = __builtin_amdgcn_fdot2(q1, u2h(kk.y), d, false);
                d = __builtin_amdgcn_fdot2(q2, u2h(kk.z), d, false);
                d = __builtin_amdgcn_fdot2(q3, u2h(kk.w), d, false);
                lg[rr][kx] = d;
            }
        }
    }
    #pragma unroll
    for (int rr=0; rr<2; ++rr) {
        const int r = w + rr*4;
        if (r <= 6) {
            #pragma unroll
            for (int kx=0; kx<K_; ++kx) S[r*K_+kx][x] = __expf(lg[rr][kx]*scale);
        }
    }
    __syncthreads();   // S complete AND all K reads of KV done

    // ---- stage V over the same buffer (loads in flight during sum below) ----
    #pragma unroll
    for (int i = 0; i < 8; ++i) {
        int e = tid + i*256;
        if (e < KVW_) {
            int pp = e / (K_*PW_);
            int rem = e - pp*(K_*PW_);
            int r = rem / PW_, xp = rem - r*PW_;
            KV[e] = vb[(size_t)pp*PPIX_ + (size_t)(y + r)*PW_ + xp];
        }
    }

    // ---- denominator: plain sum of P from LDS (overlaps V staging latency) ----
    float sum = 0.f;
    #pragma unroll
    for (int i=0;i<K2_;++i) sum += S[i][x];
    const float inv = 1.0f/sum;
    __syncthreads();   // V staged

    // ---- PV: my pair-plane (= w, 8 channels), V from LDS ----
    float4 a0 = make_float4(0.f,0.f,0.f,0.f);
    float4 a1 = make_float4(0.f,0.f,0.f,0.f);
    #pragma unroll
    for (int r=0; r<K_; ++r) {
        const uint4* row = &KV[(w*K_ + r)*PW_ + x];
        h2 ra0 = (h2)0, ra1 = (h2)0, rb0 = (h2)0, rb1 = (h2)0;
        #pragma unroll
        for (int kx=0; kx<K_; ++kx) {
            const float p = S[r*K_+kx][x];
            const h2 p2 = cvt2h(p, p);
            uint4 u = row[kx];
            ra0 += p2 * u2h(u.x);
            ra1 += p2 * u2h(u.y);
            rb0 += p2 * u2h(u.z);
            rb1 += p2 * u2h(u.w);
        }
        a0.x += (float)ra0[0]; a0.y += (float)ra0[1];
        a0.z += (float)ra1[0]; a0.w += (float)ra1[1];
        a1.x += (float)rb0[0]; a1.y += (float)rb0[1];
        a1.z += (float)rb1[0]; a1.w += (float)rb1[1];
    }
    qpl[(size_t)w*L_ + y*W_ + x] = make_uint4(pkh(a0.x*inv, a0.y*inv), pkh(a0.z*inv, a0.w*inv),
                                              pkh(a1.x*inv, a1.y*inv), pkh(a1.z*inv, a1.w*inv));
}

// ---------------- Kernel D: output projection via f16 MFMA (64-o tiles) -----
__global__ __launch_bounds__(256) void out_mfma(
    const uint4* __restrict__ qt, const unsigned* __restrict__ wb,
    const float* __restrict__ bo, float* __restrict__ out)
{
    const int b    = blockIdx.z;
    const int l0   = blockIdx.x * 64;
    const int o_t0 = blockIdx.y * 64;
    const unsigned* wbp = wb + 3*32768;
    const int tid  = threadIdx.x;
    const int lane = tid & 63, wave = tid >> 6;
    const int orow = lane & 15, kgrp = lane >> 4;

    __shared__ _Float16 Ws[64*WS_STR];    // 9.2 KB
    __shared__ _Float16 Xs[64*WS_STR];    // 9.2 KB

    f32x4 acc[4] = {};
    const int cq  = tid >> 6;
    const int lst = tid & 63;

    for (int ch = 0; ch < 4; ++ch) {
        const int c0 = ch*64;
        // Ws staging: uint4 (2 loads + 2 16B ds-writes per thread per chunk)
        #pragma unroll
        for (int i = 0; i < 2; ++i) {
            int flat = i*256 + tid;             // 0..511
            int o    = flat >> 3;               // 0..63
            int c16  = flat & 7;
            uint4 v = *reinterpret_cast<const uint4*>(wbp + (size_t)(o_t0 + o)*128 + ch*32 + c16*4);
            *reinterpret_cast<uint4*>(&Ws[o*WS_STR + c16*8]) = v;
        }
        #pragma unroll
        for (int i = 0; i < 2; ++i) {
            int c8 = i*4 + cq;                  // 8-ch group within chunk, 0..7
            uint4 v = qt[((size_t)b*32 + (c0>>3) + c8)*L_ + l0 + lst];
            *reinterpret_cast<uint4*>(&Xs[lst*WS_STR + c8*8]) = v;
        }
        __syncthreads();
        #pragma unroll
        for (int kk = 0; kk < 2; ++kk) {
            f16x8 af, bfr[4];
            af = *reinterpret_cast<const f16x8*>(&Ws[(wave*16 + orow)*WS_STR + kk*32 + kgrp*8]);
            #pragma unroll
            for (int fn = 0; fn < 4; ++fn)
                bfr[fn] = *reinterpret_cast<const f16x8*>(&Xs[(fn*16 + orow)*WS_STR + kk*32 + kgrp*8]);
            #pragma unroll
            for (int fn = 0; fn < 4; ++fn)
                acc[fn] = __builtin_amdgcn_mfma_f32_16x16x32_f16(af, bfr[fn], acc[fn], 0, 0, 0);
        }
        __syncthreads();
    }

    {
        const int o_base = o_t0 + wave*16 + kgrp*4;
        #pragma unroll
        for (int fn = 0; fn < 4; ++fn) {
            const int xl = fn*16 + orow;
            #pragma unroll
            for (int r = 0; r < 4; ++r)
                out[(size_t)(b*C_ + o_base + r)*L_ + l0 + xl] = acc[fn][r] + bo[o_base + r];
        }
    }
}

extern "C" void kernel_launch(void* const* d_in, const int* in_sizes, int n_in,
                              void* d_out, int out_size, void* d_ws, size_t ws_size,
                              hipStream_t stream) {
    const float* queries = (const float*)d_in[0];
    const float* keys    = (const float*)d_in[1];
    const float* values  = (const float*)d_in[2];
    const float* wq = (const float*)d_in[3];
    const float* bq = (const float*)d_in[4];
    const float* wk = (const float*)d_in[5];
    const float* bk = (const float*)d_in[6];
    const float* wv = (const float*)d_in[7];
    const float* bv = (const float*)d_in[8];
    const float* wo = (const float*)d_in[9];
    const float* bo = (const float*)d_in[10];
    float* out = (float*)d_out;

    uint4* qt = (uint4*)d_ws;                              // Q f16 pair-plane, attn out in-place
    uint4* kt = qt + (size_t)B_*HEADS_*NPP_*L_;            // padded pair-plane K
    uint4* vt = kt + PADT4_;                               // padded pair-plane V
    unsigned* wb = (unsigned*)(vt + PADT4_);               // f16 packed weights

    prep<<<512, 256, 0, stream>>>(wq, wk, wv, wo, wb);
    qkv_mfma<<<dim3(64, 2, 7), 256, 0, stream>>>(queries, keys, values, wb, bq, bk, bv,
                                                 (uint2*)qt, (uint2*)kt, (uint2*)vt, kt, vt);
    local_attn<<<1024, 256, 0, stream>>>(qt, kt, vt);
    out_mfma<<<dim3(64, 4, 2), 256, 0, stream>>>(qt, wb, bo, out);
}